// Round 1
// baseline (457.496 us; speedup 1.0000x reference)
//
#include <hip/hip_runtime.h>
#include <math.h>

#define B_ 2
#define N_ 2048
#define IN_DIM_ 256
#define DIM_ 256
#define H_ 8
#define DH_ 32
#define TOPK_ 4
#define EPS_ 1e-5f
#define TEMP_ 0.17677669529663687f  // 1/sqrt(32)

// ---------------- LayerNorm: one row (256 floats) per 64-lane wave ----------------
__global__ __launch_bounds__(256) void ln_kernel(const float* __restrict__ x,
                                                 const float* __restrict__ gamma,
                                                 const float* __restrict__ beta,
                                                 float* __restrict__ xn) {
  int w = threadIdx.x >> 6, ld = threadIdx.x & 63;
  int row = blockIdx.x * 4 + w;
  const float4* xr = (const float4*)(x + (size_t)row * 256);
  float4 v = xr[ld];
  float s = v.x + v.y + v.z + v.w;
  float ss = v.x * v.x + v.y * v.y + v.z * v.z + v.w * v.w;
  #pragma unroll
  for (int off = 1; off < 64; off <<= 1) {
    s += __shfl_xor(s, off);
    ss += __shfl_xor(ss, off);
  }
  float mu = s * (1.0f / 256.0f);
  float var = ss * (1.0f / 256.0f) - mu * mu;
  float rstd = rsqrtf(var + EPS_);
  float4 g = ((const float4*)gamma)[ld];
  float4 bt = ((const float4*)beta)[ld];
  float4 o;
  o.x = (v.x - mu) * rstd * g.x + bt.x;
  o.y = (v.y - mu) * rstd * g.y + bt.y;
  o.z = (v.z - mu) * rstd * g.z + bt.z;
  o.w = (v.w - mu) * rstd * g.w + bt.w;
  ((float4*)(xn + (size_t)row * 256))[ld] = o;
}

// ---------------- fp32 tiled GEMM: C[m][n] = sum_k A[m*K+k] * Bm[n*K+k] ----------------
// BM=BN=64, BK=32, 256 threads, 4x4 micro-tile per thread.
// PROJ epilogue adds vres[m*768+n] + bias[n] (residual v_flat + b_proj).
template <bool PROJ>
__global__ __launch_bounds__(256) void gemm_nt(const float* __restrict__ A,
                                               const float* __restrict__ Bm,
                                               float* __restrict__ C,
                                               const float* __restrict__ vres,
                                               const float* __restrict__ bias,
                                               int K, int ldc) {
  __shared__ float As[32][64];
  __shared__ float Bs[32][64];
  int m0 = blockIdx.x * 64, n0 = blockIdx.y * 64;
  int t = threadIdx.x;
  int tm = t & 15, tn = t >> 4;
  float acc[4][4] = {};
  for (int k0 = 0; k0 < K; k0 += 32) {
    __syncthreads();
    for (int f = t; f < 512; f += 256) {
      int row = f >> 3, j = f & 7;
      float4 a = *(const float4*)(A + (size_t)(m0 + row) * K + k0 + j * 4);
      As[j * 4 + 0][row] = a.x; As[j * 4 + 1][row] = a.y;
      As[j * 4 + 2][row] = a.z; As[j * 4 + 3][row] = a.w;
      float4 b = *(const float4*)(Bm + (size_t)(n0 + row) * K + k0 + j * 4);
      Bs[j * 4 + 0][row] = b.x; Bs[j * 4 + 1][row] = b.y;
      Bs[j * 4 + 2][row] = b.z; Bs[j * 4 + 3][row] = b.w;
    }
    __syncthreads();
    #pragma unroll
    for (int k = 0; k < 32; k++) {
      float4 a = *(const float4*)&As[k][tm * 4];
      float4 b = *(const float4*)&Bs[k][tn * 4];
      float av[4] = {a.x, a.y, a.z, a.w};
      float bv[4] = {b.x, b.y, b.z, b.w};
      #pragma unroll
      for (int i = 0; i < 4; i++)
        #pragma unroll
        for (int j = 0; j < 4; j++)
          acc[i][j] = fmaf(av[i], bv[j], acc[i][j]);
    }
  }
  #pragma unroll
  for (int i = 0; i < 4; i++) {
    int m = m0 + tm * 4 + i;
    int n = n0 + tn * 4;
    float4 r = {acc[i][0], acc[i][1], acc[i][2], acc[i][3]};
    if (PROJ) {
      float4 vr = *(const float4*)(vres + (size_t)m * 768 + n);
      float4 bb = *(const float4*)(bias + n);
      r.x += vr.x + bb.x; r.y += vr.y + bb.y;
      r.z += vr.z + bb.z; r.w += vr.w + bb.w;
    }
    *(float4*)(C + (size_t)m * ldc + n) = r;
  }
}

// ---------------- Flash attention + top-4 tracking ----------------
// Grid: (N/64, H, B). Block 256 threads. Thread t: qr=t>>2 (query row in tile),
// qc=t&3 (owns dims qc*8..qc*8+7 of output, computes s-columns qc*16..qc*16+15).
__global__ __launch_bounds__(256) void attn_kernel(const float* __restrict__ qkv,
                                                   float* __restrict__ msg,
                                                   float* __restrict__ out_s,
                                                   float* __restrict__ out_i) {
  const int l0 = blockIdx.x * 64;
  const int h = blockIdx.y;
  const int b = blockIdx.z;
  const int t = threadIdx.x;
  const int qr = t >> 2, qc = t & 3;

  __shared__ float4 Ks[64][8];
  __shared__ float4 Vs[64][8];
  __shared__ float Ps[64][65];  // padded: PV-phase reads conflict-free

  const size_t rowstride = 3 * H_ * DH_;  // 768
  const float* qrow = qkv + ((size_t)(b * N_) + l0 + qr) * rowstride + h * DH_;
  float4 qreg[8];
  #pragma unroll
  for (int j = 0; j < 8; j++) {
    float4 v = ((const float4*)qrow)[j];
    v.x *= TEMP_; v.y *= TEMP_; v.z *= TEMP_; v.w *= TEMP_;
    qreg[j] = v;
  }
  float4 o0 = {0, 0, 0, 0}, o1 = {0, 0, 0, 0};
  float m = -INFINITY, l = 0.f;
  float tv[TOPK_];
  int ti[TOPK_];
  #pragma unroll
  for (int i = 0; i < TOPK_; i++) { tv[i] = -INFINITY; ti[i] = 0x7fffffff; }

  const float* kbase = qkv + (size_t)(b * N_) * rowstride + 256 + h * DH_;

  for (int s0 = 0; s0 < N_; s0 += 64) {
    __syncthreads();  // protect Ks/Vs from previous tile's PV reads
    for (int f = t; f < 512; f += 256) {
      int row = f >> 3, j = f & 7;
      const float* kp = kbase + (size_t)(s0 + row) * rowstride + j * 4;
      Ks[row][j] = *(const float4*)kp;
      Vs[row][j] = *(const float4*)(kp + 256);  // V block is +H*DH after K block
    }
    __syncthreads();

    float pj[16];
    float tmax = -INFINITY;
    #pragma unroll
    for (int j = 0; j < 16; j++) {
      int ss = qc * 16 + j;
      float4 a = {0, 0, 0, 0};
      #pragma unroll
      for (int kk = 0; kk < 8; kk++) {
        int kx = (kk + 2 * qc) & 7;  // bank swizzle across lane quarters
        float4 kv = Ks[ss][kx];
        float4 qv = qreg[kx];
        a.x = fmaf(qv.x, kv.x, a.x);
        a.y = fmaf(qv.y, kv.y, a.y);
        a.z = fmaf(qv.z, kv.z, a.z);
        a.w = fmaf(qv.w, kv.w, a.w);
      }
      float sval = (a.x + a.y) + (a.z + a.w);
      pj[j] = sval;
      tmax = fmaxf(tmax, sval);
      int idx = s0 + ss;
      // running top-4 (descending; ties -> lower index first, matching lax.top_k)
      if (sval > tv[3] || (sval == tv[3] && idx < ti[3])) {
        int pos = 3;
        while (pos > 0 && (sval > tv[pos - 1] ||
                           (sval == tv[pos - 1] && idx < ti[pos - 1]))) {
          tv[pos] = tv[pos - 1];
          ti[pos] = ti[pos - 1];
          pos--;
        }
        tv[pos] = sval;
        ti[pos] = idx;
      }
    }
    tmax = fmaxf(tmax, __shfl_xor(tmax, 1));
    tmax = fmaxf(tmax, __shfl_xor(tmax, 2));
    float mnew = fmaxf(m, tmax);
    float alpha = __expf(m - mnew);
    float psum = 0.f;
    #pragma unroll
    for (int j = 0; j < 16; j++) {
      float p = __expf(pj[j] - mnew);
      Ps[qr][qc * 16 + j] = p;
      psum += p;
    }
    psum += __shfl_xor(psum, 1);
    psum += __shfl_xor(psum, 2);
    l = l * alpha + psum;
    m = mnew;
    o0.x *= alpha; o0.y *= alpha; o0.z *= alpha; o0.w *= alpha;
    o1.x *= alpha; o1.y *= alpha; o1.z *= alpha; o1.w *= alpha;
    // PV: Ps row written/read by same 4-lane group (same wave) -> no barrier needed
    #pragma unroll
    for (int s = 0; s < 64; s++) {
      float p = Ps[qr][s];
      float4 v0 = Vs[s][qc * 2];
      float4 v1 = Vs[s][qc * 2 + 1];
      o0.x = fmaf(p, v0.x, o0.x); o0.y = fmaf(p, v0.y, o0.y);
      o0.z = fmaf(p, v0.z, o0.z); o0.w = fmaf(p, v0.w, o0.w);
      o1.x = fmaf(p, v1.x, o1.x); o1.y = fmaf(p, v1.y, o1.y);
      o1.z = fmaf(p, v1.z, o1.z); o1.w = fmaf(p, v1.w, o1.w);
    }
  }

  // merge per-lane top-4 across the 4 lanes of this row (same wave -> LDS, no barrier)
  #pragma unroll
  for (int i = 0; i < 4; i++) {
    Ps[qr][qc * 4 + i] = tv[i];
    ((int*)&Ps[qr][16])[qc * 4 + i] = ti[i];
  }
  float mv[16];
  int mi[16];
  #pragma unroll
  for (int e = 0; e < 16; e++) {
    mv[e] = Ps[qr][e];
    mi[e] = ((int*)&Ps[qr][16])[e];
  }
  float fv[4];
  int fi[4];
  #pragma unroll
  for (int r = 0; r < 4; r++) {
    float best = -INFINITY;
    int bi = 0x7fffffff, bp = 0;
    #pragma unroll
    for (int e = 0; e < 16; e++) {
      if (mv[e] > best || (mv[e] == best && mi[e] < bi)) {
        best = mv[e]; bi = mi[e]; bp = e;
      }
    }
    fv[r] = best; fi[r] = bi;
    mv[bp] = -INFINITY; mi[bp] = 0x7fffffff;
  }

  float linv = 1.0f / l;
  o0.x *= linv; o0.y *= linv; o0.z *= linv; o0.w *= linv;
  o1.x *= linv; o1.y *= linv; o1.z *= linv; o1.w *= linv;

  float sc[4];
  #pragma unroll
  for (int r = 0; r < 4; r++) {
    sc[r] = __expf(fv[r] - m) * linv;
    const float* vp =
        qkv + ((size_t)(b * N_) + fi[r]) * rowstride + 512 + h * DH_ + qc * 8;
    float4 v0 = *(const float4*)vp;
    float4 v1 = *(const float4*)(vp + 4);
    o0.x = fmaf(-sc[r], v0.x, o0.x); o0.y = fmaf(-sc[r], v0.y, o0.y);
    o0.z = fmaf(-sc[r], v0.z, o0.z); o0.w = fmaf(-sc[r], v0.w, o0.w);
    o1.x = fmaf(-sc[r], v1.x, o1.x); o1.y = fmaf(-sc[r], v1.y, o1.y);
    o1.z = fmaf(-sc[r], v1.z, o1.z); o1.w = fmaf(-sc[r], v1.w, o1.w);
  }

  float* mp = msg + ((size_t)(b * N_) + l0 + qr) * DIM_ + h * DH_ + qc * 8;
  *(float4*)mp = o0;
  *(float4*)(mp + 4) = o1;

  if (qc == 0) {
    size_t base = ((size_t)(b * N_ + l0 + qr)) * TOPK_;
    #pragma unroll
    for (int r = 0; r < 4; r++) {
      out_s[(base + r) * H_ + h] = sc[r];
      out_i[(base + r) * H_ + h] = (float)fi[r];
    }
  }
}

extern "C" void kernel_launch(void* const* d_in, const int* in_sizes, int n_in,
                              void* d_out, int out_size, void* d_ws, size_t ws_size,
                              hipStream_t stream) {
  const float* points = (const float*)d_in[0];
  const float* norm_gamma = (const float*)d_in[1];
  const float* norm_beta = (const float*)d_in[2];
  const float* w_qkv = (const float*)d_in[3];
  const float* w_proj = (const float*)d_in[4];
  const float* b_proj = (const float*)d_in[5];

  float* out0 = (float*)d_out;                       // message_flat (4096*256)
  float* out1 = out0 + (size_t)4096 * 256;           // topk_score (4096*4*8)
  float* out2 = out1 + (size_t)4096 * 4 * 8;         // topk_idx as float

  float* xn = (float*)d_ws;                          // 4096*256
  float* qkv = xn + (size_t)4096 * 256;              // 4096*768
  float* msg = qkv + (size_t)4096 * 768;             // 4096*256

  ln_kernel<<<1024, 256, 0, stream>>>(points, norm_gamma, norm_beta, xn);
  gemm_nt<false><<<dim3(64, 12), 256, 0, stream>>>(xn, w_qkv, qkv, nullptr,
                                                   nullptr, 256, 768);
  attn_kernel<<<dim3(N_ / 64, H_, B_), 256, 0, stream>>>(qkv, msg, out1, out2);
  gemm_nt<true><<<dim3(64, 4), 256, 0, stream>>>(msg, w_proj, out0, qkv + 512,
                                                 b_proj, 256, 256);
}